// Round 10
// baseline (274.448 us; speedup 1.0000x reference)
//
#include <hip/hip_runtime.h>
#include <cstdint>

typedef int   i32x4 __attribute__((ext_vector_type(4)));
typedef int   i32x8 __attribute__((ext_vector_type(8)));
typedef float f32x4 __attribute__((ext_vector_type(4)));

static constexpr int N_IMG = 32, HWP = 3136, KK = 2304, HP = 58;
static constexpr size_t XPAD_BYTES = (size_t)N_IMG * HP * HP * 256;   // 27,557,888
static constexpr size_t OFF_XPAD = 0;
static constexpr size_t OFF_WSGN = XPAD_BYTES;                         // +589,824
static constexpr size_t OFF_MSC  = OFF_WSGN + (size_t)256 * KK;
static constexpr size_t OFF_ACC  = OFF_MSC + 1024;

__device__ __forceinline__ void async16(const void* g, const void* l) {
    __builtin_amdgcn_global_load_lds(
        (const __attribute__((address_space(1))) uint32_t*)g,
        (__attribute__((address_space(3))) uint32_t*)l, 16, 0, 0);
}

__device__ __forceinline__ unsigned char sign_fp8(float v) {
    return (v > 0.f) ? 0x38u : ((v < 0.f) ? 0xB8u : 0u);   // e4m3: +1 / -1 / 0
}

// X-tile K-slice byte offset within a padded NHWC row for K-step kt (K=128)
__device__ __forceinline__ int xoff(int kt) {
    int rs = kt >> 1, rr = rs / 3, ss = rs - rr * 3;
    return (rr * HP + ss) * 256 + ((kt & 1) << 7);
}

// ---- K1: weights -> signs in [kt][row 0..255][128B] layout + msc + zero acc32 ----
__global__ __launch_bounds__(256) void k_wm(const float* __restrict__ w,
                                            unsigned char* __restrict__ wA,
                                            float* __restrict__ msc,
                                            float* __restrict__ acc32) {
    int ko = blockIdx.x, t = threadIdx.x;
    __shared__ unsigned char s[2304];
    __shared__ float red[4];
    float sum = 0.f;
    #pragma unroll
    for (int i = 0; i < 9; ++i) {
        float v = w[(size_t)ko * KK + i * 256 + t];   // flat idx = c*9+rs order
        sum += fabsf(v);
        s[i * 256 + t] = sign_fp8(v);
    }
    #pragma unroll
    for (int off = 32; off; off >>= 1) sum += __shfl_down(sum, off, 64);
    if ((t & 63) == 0) red[t >> 6] = sum;
    __syncthreads();
    if (t == 0) msc[ko] = (red[0] + red[1] + red[2] + red[3]) * (1.f / 2304.f);
    if (ko == 0 && t < 32) acc32[t] = 0.f;
    // k = rs*256 + c with rs=i, c=t ; value = s[t*9+i] = sign(w[ko][c=t][rs=i])
    #pragma unroll
    for (int i = 0; i < 9; ++i)
        wA[((size_t)(i * 2 + (t >> 7)) * 256 + ko) * 128 + (t & 127)] = s[t * 9 + i];
}

// ---- K2: x -> signs (fp8, padded NHWC) + per-sample |x| sum + halo clear ----
// v3: full-line stores (verified R4: removed xpad from the hot list).
__global__ __launch_bounds__(256) void k_xpad(const float* __restrict__ x,
                                              unsigned char* __restrict__ xpad,
                                              float* __restrict__ acc32) {
    int bx = blockIdx.x, n = blockIdx.y;          // bx: 0..48 hw-tile
    int t = threadIdx.x;
    {
        int g = (n * 49 + bx) * 256 + t;
        if (g < 32 * 228 * 16) {
            int n2 = g / 3648, rem = g - n2 * 3648;
            int pos = rem >> 4, j = rem & 15;
            int h, wq;
            if (pos < 58)       { h = 0;         wq = pos; }
            else if (pos < 116) { h = 57;        wq = pos - 58; }
            else if (pos < 172) { h = pos - 115; wq = 0; }
            else                { h = pos - 171; wq = 57; }
            *(i32x4*)&xpad[(((size_t)n2 * HP + h) * HP + wq) * 256 + j * 16] =
                (i32x4){0, 0, 0, 0};
        }
    }
    int hw0 = bx * 64;
    int cg = t & 15, hwg = t >> 4;                // cg: 16-channel group, hwg: 0..15
    int c16 = cg * 16;
    int hwb = hw0 + hwg * 4;                      // 4 consecutive hw, never crosses a row

    f32x4 v[16];
    #pragma unroll
    for (int jc = 0; jc < 16; ++jc)
        v[jc] = *(const f32x4*)&x[((size_t)(n * 256 + c16 + jc)) * HWP + hwb];

    float asum = 0.f;
    #pragma unroll
    for (int jc = 0; jc < 16; ++jc)
        #pragma unroll
        for (int k = 0; k < 4; ++k) asum += fabsf(v[jc][k]);

    int h = hwb / 56, wp = hwb - h * 56;
    unsigned char* dst = &xpad[(((size_t)n * HP + h + 1) * HP + (wp + 1)) * 256 + c16];
    #pragma unroll
    for (int k = 0; k < 4; ++k) {                 // k: hw within the 4-group
        i32x4 pk;
        #pragma unroll
        for (int q = 0; q < 4; ++q) {             // q: dword = channels c16+4q..+3
            pk[q] = (int)((unsigned)sign_fp8(v[4 * q + 0][k])
                        | ((unsigned)sign_fp8(v[4 * q + 1][k]) << 8)
                        | ((unsigned)sign_fp8(v[4 * q + 2][k]) << 16)
                        | ((unsigned)sign_fp8(v[4 * q + 3][k]) << 24));
        }
        *(i32x4*)(dst + (size_t)k * 256) = pk;    // 16 lanes = full 256B row
    }

    #pragma unroll
    for (int off = 32; off; off >>= 1) asum += __shfl_down(asum, off, 64);
    __shared__ float red[4];
    if ((t & 63) == 0) red[t >> 6] = asum;
    __syncthreads();
    if (t == 0) atomicAdd(&acc32[n], red[0] + red[1] + red[2] + red[3]);
}

// ---- K3: MX-fp8 implicit GEMM, v7: T4 counted-vmcnt pipeline (never drain
// in main loop). R8 geometry (512thr/8 waves, 256ko x 128p, 2x48KB dbuf,
// 1 blk/CU) + the m218 ingredient R8 lacked: loads stay in flight ACROSS
// barriers. Per step: issue 6 loads/wave (kt+1 -> nxt) -> vmcnt(6) [kt's
// landed, kt+1's in flight] -> raw s_barrier -> ds_read+MFMA (setprio) ->
// lgkmcnt(0)+sched_barrier [pin reads: next overwrite is safe] -> s_barrier.
// NO __syncthreads in loop (its mandatory vmcnt(0) drain IS the old wall).
__global__ __launch_bounds__(512, 2) void k_gemm(const unsigned char* __restrict__ wA,
                                                 const unsigned char* __restrict__ xpad,
                                                 const float* __restrict__ acc32,
                                                 const float* __restrict__ msc,
                                                 float* __restrict__ out) {
    extern __shared__ __attribute__((aligned(16))) unsigned char smem[];  // 2 x 49152
    const int t = threadIdx.x;
    const int lane = t & 63, wv = t >> 6;          // wv 0..7
    const int ntile = blockIdx.x;
    const int quad = lane >> 4, r16 = lane & 15;
    const int wm = wv & 3, wn = wv >> 2;           // ko quadrant / p half

    // staging swizzle (verified): slot = 1024B; lane l writes slot+l*16 ->
    // row = slot*8+(l>>3), phys chunk = l&7; logical chunk kc at phys perm(kc)^sw,
    // sw=row&7; source kc = invperm((l&7)^(l>>3)), invperm(p)=((p&3)<<1)|(p>>2).
    const int lrow = lane >> 3;
    const int pxs  = (lane & 7) ^ lrow;
    const int kc   = ((pxs & 3) << 1) | (pxs >> 2);

    const unsigned char* wp[4];
    int ldsWoff[4];
    #pragma unroll
    for (int rnd = 0; rnd < 4; ++rnd) {
        int s = wv * 4 + rnd;                      // 0..31
        int row = s * 8 + lrow;                    // ko 0..255
        wp[rnd] = wA + (size_t)row * 128 + kc * 16;   // + kt*32768
        ldsWoff[rnd] = s * 1024;
    }
    const unsigned char* xp[2];
    int ldsXoff[2];
    #pragma unroll
    for (int rnd = 0; rnd < 2; ++rnd) {
        int s = wv * 2 + rnd;                      // 0..15
        int row = s * 8 + lrow;                    // p-row 0..127
        int p = ntile * 128 + row;
        int nimg = p / HWP, hw = p - nimg * HWP;
        int h = hw / 56, wpos = hw - h * 56;
        xp[rnd] = xpad + (((size_t)nimg * HP + h) * HP + wpos) * 256 + kc * 16;
        ldsXoff[rnd] = 32768 + s * 1024;
    }

    f32x4 acc[4][4];
    #pragma unroll
    for (int i = 0; i < 4; ++i)
        #pragma unroll
        for (int j = 0; j < 4; ++j)
            acc[i][j] = (f32x4){0.f, 0.f, 0.f, 0.f};

    // prologue: issue stage kt=0 into buf0 — NO drain (vmcnt(6) in step 0 covers it)
    {
        const int offX = xoff(0);
        #pragma unroll
        for (int rnd = 0; rnd < 4; ++rnd) async16(wp[rnd], smem + ldsWoff[rnd]);
        #pragma unroll
        for (int rnd = 0; rnd < 2; ++rnd) async16(xp[rnd] + offX, smem + ldsXoff[rnd]);
    }

    for (int kt = 0; kt < 18; ++kt) {
        unsigned char* cb = smem + (size_t)(kt & 1) * 49152;       // compute buffer
        if (kt < 17) {                                             // prefetch kt+1
            unsigned char* nb = smem + (size_t)((kt & 1) ^ 1) * 49152;
            const size_t offW = (size_t)(kt + 1) * 32768;
            const int offX = xoff(kt + 1);
            #pragma unroll
            for (int rnd = 0; rnd < 4; ++rnd) async16(wp[rnd] + offW, nb + ldsWoff[rnd]);
            #pragma unroll
            for (int rnd = 0; rnd < 2; ++rnd) async16(xp[rnd] + offX, nb + ldsXoff[rnd]);
            asm volatile("s_waitcnt vmcnt(6)" ::: "memory");       // kt landed; kt+1 in flight
        } else {
            asm volatile("s_waitcnt vmcnt(0)" ::: "memory");       // last tile
        }
        __builtin_amdgcn_s_barrier();              // all waves' kt data visible
        __builtin_amdgcn_sched_barrier(0);         // no ds_read hoists above

        // reads: lo at phys (q^sw), hi at ((q|4)^sw) — bit-2 pair, measured 0-conflict
        const unsigned char* Wt = cb;
        const unsigned char* Xt = cb + 32768;
        i32x8 a8[4];
        #pragma unroll
        for (int i = 0; i < 4; ++i) {
            int row = wm * 64 + i * 16 + r16, sw = row & 7;   // ko row 0..255
            i32x4 lo = *(const i32x4*)(Wt + row * 128 + ((quad ^ sw) << 4));
            i32x4 hi = *(const i32x4*)(Wt + row * 128 + (((quad | 4) ^ sw) << 4));
            a8[i] = __builtin_shufflevector(lo, hi, 0, 1, 2, 3, 4, 5, 6, 7);
        }
        __builtin_amdgcn_s_setprio(1);
        #pragma unroll
        for (int j = 0; j < 4; ++j) {
            int row = wn * 64 + j * 16 + r16, sw = row & 7;   // p row 0..127
            i32x4 lo = *(const i32x4*)(Xt + row * 128 + ((quad ^ sw) << 4));
            i32x4 hi = *(const i32x4*)(Xt + row * 128 + (((quad | 4) ^ sw) << 4));
            i32x8 b8 = __builtin_shufflevector(lo, hi, 0, 1, 2, 3, 4, 5, 6, 7);
            #pragma unroll
            for (int i = 0; i < 4; ++i)
                acc[i][j] = __builtin_amdgcn_mfma_scale_f32_16x16x128_f8f6f4(
                    a8[i], b8, acc[i][j], 0, 0, 0, 127, 0, 127);
        }
        __builtin_amdgcn_s_setprio(0);

        // pin all LDS reads complete before the barrier (rule #18), so next
        // step's staging may overwrite this buffer safely.
        asm volatile("s_waitcnt lgkmcnt(0)" ::: "memory");
        __builtin_amdgcn_sched_barrier(0);
        __builtin_amdgcn_s_barrier();
    }

    // epilogue: D row (quad*4+reg)=ko (wave owns ko 64*wm..), D col (lane&15)=p
    float mscv[4][4];
    #pragma unroll
    for (int i = 0; i < 4; ++i) {
        int ko0 = wm * 64 + i * 16 + quad * 4;
        #pragma unroll
        for (int r = 0; r < 4; ++r) mscv[i][r] = msc[ko0 + r];
    }
    #pragma unroll
    for (int j = 0; j < 4; ++j) {
        int p = ntile * 128 + wn * 64 + j * 16 + r16;
        int nimg = p / HWP, hw = p - nimg * HWP;
        float av = fmaxf(acc32[nimg] * (2.f / 802816.f), 1e-5f);
        float* outp = out + (size_t)nimg * 802816 + hw;
        #pragma unroll
        for (int i = 0; i < 4; ++i) {
            int ko0 = wm * 64 + i * 16 + quad * 4;
            #pragma unroll
            for (int r = 0; r < 4; ++r)
                outp[(size_t)(ko0 + r) * HWP] = acc[i][j][r] * av * mscv[i][r];
        }
    }
}

extern "C" void kernel_launch(void* const* d_in, const int* in_sizes, int n_in,
                              void* d_out, int out_size, void* d_ws, size_t ws_size,
                              hipStream_t stream) {
    const float* x = (const float*)d_in[0];
    const float* w = (const float*)d_in[1];
    float* out = (float*)d_out;
    char* ws = (char*)d_ws;
    unsigned char* xpad = (unsigned char*)(ws + OFF_XPAD);
    unsigned char* wA   = (unsigned char*)(ws + OFF_WSGN);
    float* msc   = (float*)(ws + OFF_MSC);
    float* acc32 = (float*)(ws + OFF_ACC);

    static bool lds_opt_in = false;
    if (!lds_opt_in) {   // host-side attribute set, not a stream op (graph-safe)
        hipFuncSetAttribute((const void*)k_gemm,
                            hipFuncAttributeMaxDynamicSharedMemorySize, 98304);
        lds_opt_in = true;
    }

    k_wm<<<256, 256, 0, stream>>>(w, wA, msc, acc32);
    k_xpad<<<dim3(49, N_IMG), 256, 0, stream>>>(x, xpad, acc32);
    k_gemm<<<784, 512, 98304, stream>>>(wA, xpad, acc32, msc, out);
}

// Round 11
// 226.585 us; speedup vs baseline: 1.2112x; 1.2112x over previous
//
#include <hip/hip_runtime.h>
#include <cstdint>

typedef int      i32x4 __attribute__((ext_vector_type(4)));
typedef int      i32x8 __attribute__((ext_vector_type(8)));
typedef float    f32x4 __attribute__((ext_vector_type(4)));
typedef unsigned u32x2 __attribute__((ext_vector_type(2)));

static constexpr int N_IMG = 32, HWP = 3136, KK = 2304, HP = 58;
// fp4 nibble-packed xpad: row (n,h,w) = 256 channels * 4b = 128B
static constexpr size_t XPAD_BYTES = (size_t)N_IMG * HP * HP * 128;   // 13,778,944
static constexpr size_t OFF_XPAD = 0;
static constexpr size_t OFF_WSGN = XPAD_BYTES;                         // + 9*256*128 = 294,912
static constexpr size_t OFF_MSC  = OFF_WSGN + (size_t)9 * 256 * 128;
static constexpr size_t OFF_ACC  = OFF_MSC + 1024;

__device__ __forceinline__ void async16(const void* g, const void* l) {
    __builtin_amdgcn_global_load_lds(
        (const __attribute__((address_space(1))) uint32_t*)g,
        (__attribute__((address_space(3))) uint32_t*)l, 16, 0, 0);
}

// fp4 e2m1 sign nibble: +1 = 0x2, -1 = 0xA, 0 = 0x0
__device__ __forceinline__ unsigned sgn4(float v) {
    return (v > 0.f) ? 0x2u : ((v < 0.f) ? 0xAu : 0u);
}

__device__ __forceinline__ i32x8 pad8(i32x4 v) {
    return __builtin_shufflevector(v, (i32x4){0, 0, 0, 0}, 0, 1, 2, 3, 4, 5, 6, 7);
}

// ---- K1: weights -> fp4 sign nibbles in [rs][ko 0..255][128B] + msc + zero acc32 ----
__global__ __launch_bounds__(256) void k_wm(const float* __restrict__ w,
                                            unsigned char* __restrict__ wA,
                                            float* __restrict__ msc,
                                            float* __restrict__ acc32) {
    int ko = blockIdx.x, t = threadIdx.x;
    __shared__ unsigned char s[2304];     // nibble code per flat w-index (c*9+rs)
    __shared__ float red[4];
    float sum = 0.f;
    #pragma unroll
    for (int i = 0; i < 9; ++i) {
        float v = w[(size_t)ko * KK + i * 256 + t];   // flat idx = c*9+rs order
        sum += fabsf(v);
        s[i * 256 + t] = (unsigned char)sgn4(v);
    }
    #pragma unroll
    for (int off = 32; off; off >>= 1) sum += __shfl_down(sum, off, 64);
    if ((t & 63) == 0) red[t >> 6] = sum;
    __syncthreads();
    if (t == 0) msc[ko] = (red[0] + red[1] + red[2] + red[3]) * (1.f / 2304.f);
    if (ko == 0 && t < 32) acc32[t] = 0.f;
    // row (rs=i, ko): byte b = channels 2b (lo nibble) | 2b+1 (hi); s[c*9+i] = sign(w[ko][c][i])
    if (t < 128) {
        #pragma unroll
        for (int i = 0; i < 9; ++i) {
            unsigned char b = (unsigned char)(s[(2 * t) * 9 + i] | (s[(2 * t + 1) * 9 + i] << 4));
            wA[((size_t)i * 256 + ko) * 128 + t] = b;
        }
    }
}

// ---- K2: x -> fp4 sign nibbles (padded NHWC, 128B rows) + |x| sum + halo clear ----
// Full-line stores kept (R4 win): 16 lanes x 8B = one whole 128B row per store.
__global__ __launch_bounds__(256) void k_xpad(const float* __restrict__ x,
                                              unsigned char* __restrict__ xpad,
                                              float* __restrict__ acc32) {
    int bx = blockIdx.x, n = blockIdx.y;          // bx: 0..48 hw-tile
    int t = threadIdx.x;
    {   // halo: 228 border cells * 8 chunks of 16B
        int g = (n * 49 + bx) * 256 + t;
        if (g < 32 * 228 * 8) {
            int n2 = g / 1824, rem = g - n2 * 1824;
            int pos = rem >> 3, j = rem & 7;
            int h, wq;
            if (pos < 58)       { h = 0;         wq = pos; }
            else if (pos < 116) { h = 57;        wq = pos - 58; }
            else if (pos < 172) { h = pos - 115; wq = 0; }
            else                { h = pos - 171; wq = 57; }
            *(i32x4*)&xpad[(((size_t)n2 * HP + h) * HP + wq) * 128 + j * 16] =
                (i32x4){0, 0, 0, 0};
        }
    }
    int hw0 = bx * 64;
    int cg = t & 15, hwg = t >> 4;                // cg: 16-channel group, hwg: 0..15
    int c16 = cg * 16;
    int hwb = hw0 + hwg * 4;                      // 4 consecutive hw, never crosses a row

    f32x4 v[16];
    #pragma unroll
    for (int jc = 0; jc < 16; ++jc)
        v[jc] = *(const f32x4*)&x[((size_t)(n * 256 + c16 + jc)) * HWP + hwb];

    float asum = 0.f;
    #pragma unroll
    for (int jc = 0; jc < 16; ++jc)
        #pragma unroll
        for (int k = 0; k < 4; ++k) asum += fabsf(v[jc][k]);

    int h = hwb / 56, wp = hwb - h * 56;
    unsigned char* dst = &xpad[(((size_t)n * HP + h + 1) * HP + (wp + 1)) * 128 + cg * 8];
    #pragma unroll
    for (int k = 0; k < 4; ++k) {                 // k: hw within the 4-group
        unsigned lo = 0, hi = 0;
        #pragma unroll
        for (int j = 0; j < 8; ++j) lo |= sgn4(v[j][k]) << (4 * j);
        #pragma unroll
        for (int j = 0; j < 8; ++j) hi |= sgn4(v[8 + j][k]) << (4 * j);
        *(u32x2*)(dst + (size_t)k * 128) = (u32x2){lo, hi};   // 16 lanes = full 128B row
    }

    #pragma unroll
    for (int off = 32; off; off >>= 1) asum += __shfl_down(asum, off, 64);
    __shared__ float red[4];
    if ((t & 63) == 0) red[t >> 6] = asum;
    __syncthreads();
    if (t == 0) atomicAdd(&acc32[n], red[0] + red[1] + red[2] + red[3]);
}

// ---- K3: MX-fp4 implicit GEMM (R6 geometry, proven best: 256 thr, 48KB LDS,
// 2 blocks/CU, 2-barrier loop). fp4 halves MFMA time + staged bytes; K=256
// nibbles per 128B row -> 9 macro-steps (half the barrier events), 2 MFMA
// sub-rounds each (cbsz=blgp=4, lane k = 32*(l>>4)+nibble). Staging swizzle
// unchanged; reads pair logical chunks (q, q+4) via perm(q)^sw / perm(q+4)^sw.
__global__ __launch_bounds__(256, 2) void k_gemm(const unsigned char* __restrict__ wA,
                                                 const unsigned char* __restrict__ xpad,
                                                 const float* __restrict__ acc32,
                                                 const float* __restrict__ msc,
                                                 float* __restrict__ out) {
    __shared__ __attribute__((aligned(16))) unsigned char Wt[256 * 128];   // 256 ko x K256 nibbles
    __shared__ __attribute__((aligned(16))) unsigned char Xt[128 * 128];   // 128 p  x K256 nibbles
    const int t = threadIdx.x;
    const int lane = t & 63, wv = t >> 6;
    const int ntile = blockIdx.x;
    const int quad = lane >> 4, r16 = lane & 15;

    // staging swizzle (verified): lane l fills slot base + l*16 -> row = slot*8+(l>>3),
    // phys chunk = l&7; logical chunk kc stored at phys perm(kc)^sw, sw=row&7,
    // source kc = invperm((l&7)^(l>>3)), invperm(p)=((p&3)<<1)|(p>>2).
    const int lrow = lane >> 3;
    const int pxs  = (lane & 7) ^ lrow;
    const int kc   = ((pxs & 3) << 1) | (pxs >> 2);
    // read phys chunks for logical (quad) and (quad+4): perm(c)=(c>>1)|((c&1)<<2)
    const int pq  = (quad >> 1) | ((quad & 1) << 2);
    const int pq4 = pq ^ 2;

    const unsigned char* wp[8];
    unsigned char* ldsW[8];
    #pragma unroll
    for (int rnd = 0; rnd < 8; ++rnd) {
        int s = wv * 8 + rnd;                      // 0..31
        int row = s * 8 + lrow;                    // ko 0..255
        wp[rnd] = wA + (size_t)row * 128 + kc * 16;   // + rs*32768
        ldsW[rnd] = Wt + s * 1024;
    }
    const unsigned char* xp[4];
    unsigned char* ldsX[4];
    #pragma unroll
    for (int rnd = 0; rnd < 4; ++rnd) {
        int s = wv * 4 + rnd;                      // 0..15
        int row = s * 8 + lrow;                    // p-row 0..127
        int p = ntile * 128 + row;
        int nimg = p / HWP, hw = p - nimg * HWP;
        int h = hw / 56, wpos = hw - h * 56;
        xp[rnd] = xpad + (((size_t)nimg * HP + h) * HP + wpos) * 128 + kc * 16;
        ldsX[rnd] = Xt + s * 1024;
    }

    f32x4 acc[4][8];
    #pragma unroll
    for (int i = 0; i < 4; ++i)
        #pragma unroll
        for (int j = 0; j < 8; ++j)
            acc[i][j] = (f32x4){0.f, 0.f, 0.f, 0.f};

    for (int rs = 0; rs < 9; ++rs) {
        const int rr = rs / 3, ss = rs - rr * 3;
        const size_t offW = (size_t)rs * 32768;
        const int offX = (rr * HP + ss) * 128;
        #pragma unroll
        for (int rnd = 0; rnd < 8; ++rnd) async16(wp[rnd] + offW, ldsW[rnd]);
        #pragma unroll
        for (int rnd = 0; rnd < 4; ++rnd) async16(xp[rnd] + offX, ldsX[rnd]);
        asm volatile("s_waitcnt vmcnt(0)" ::: "memory");
        __syncthreads();

        // a fragments: lo = K 0..127 (chunk quad), hi = K 128..255 (chunk quad+4)
        i32x4 alo[4], ahi[4];
        #pragma unroll
        for (int i = 0; i < 4; ++i) {
            int row = wv * 64 + i * 16 + r16, sw = row & 7;   // ko row 0..255
            alo[i] = *(const i32x4*)(Wt + row * 128 + ((pq ^ sw) << 4));
            ahi[i] = *(const i32x4*)(Wt + row * 128 + ((pq4 ^ sw) << 4));
        }
        #pragma unroll
        for (int j = 0; j < 8; ++j) {
            int row = j * 16 + r16, sw = row & 7;             // p row 0..127
            i32x4 blo = *(const i32x4*)(Xt + row * 128 + ((pq ^ sw) << 4));
            i32x4 bhi = *(const i32x4*)(Xt + row * 128 + ((pq4 ^ sw) << 4));
            i32x8 bl8 = pad8(blo), bh8 = pad8(bhi);
            #pragma unroll
            for (int i = 0; i < 4; ++i)
                acc[i][j] = __builtin_amdgcn_mfma_scale_f32_16x16x128_f8f6f4(
                    pad8(alo[i]), bl8, acc[i][j], 4, 4, 0, 127, 0, 127);
            #pragma unroll
            for (int i = 0; i < 4; ++i)
                acc[i][j] = __builtin_amdgcn_mfma_scale_f32_16x16x128_f8f6f4(
                    pad8(ahi[i]), bh8, acc[i][j], 4, 4, 0, 127, 0, 127);
        }
        __syncthreads();
    }

    // epilogue: D row (quad*4+reg)=ko (wave owns ko 64*wv..64*wv+63), D col (lane&15)=p
    float mscv[4][4];
    #pragma unroll
    for (int i = 0; i < 4; ++i) {
        int ko0 = wv * 64 + i * 16 + quad * 4;
        #pragma unroll
        for (int r = 0; r < 4; ++r) mscv[i][r] = msc[ko0 + r];
    }
    #pragma unroll
    for (int j = 0; j < 8; ++j) {
        int p = ntile * 128 + j * 16 + r16;
        int nimg = p / HWP, hw = p - nimg * HWP;
        float av = fmaxf(acc32[nimg] * (2.f / 802816.f), 1e-5f);
        float* outp = out + (size_t)nimg * 802816 + hw;
        #pragma unroll
        for (int i = 0; i < 4; ++i) {
            int ko0 = wv * 64 + i * 16 + quad * 4;
            #pragma unroll
            for (int r = 0; r < 4; ++r)
                outp[(size_t)(ko0 + r) * HWP] = acc[i][j][r] * av * mscv[i][r];
        }
    }
}

extern "C" void kernel_launch(void* const* d_in, const int* in_sizes, int n_in,
                              void* d_out, int out_size, void* d_ws, size_t ws_size,
                              hipStream_t stream) {
    const float* x = (const float*)d_in[0];
    const float* w = (const float*)d_in[1];
    float* out = (float*)d_out;
    char* ws = (char*)d_ws;
    unsigned char* xpad = (unsigned char*)(ws + OFF_XPAD);
    unsigned char* wA   = (unsigned char*)(ws + OFF_WSGN);
    float* msc   = (float*)(ws + OFF_MSC);
    float* acc32 = (float*)(ws + OFF_ACC);

    k_wm<<<256, 256, 0, stream>>>(w, wA, msc, acc32);
    k_xpad<<<dim3(49, N_IMG), 256, 0, stream>>>(x, xpad, acc32);
    k_gemm<<<784, 256, 0, stream>>>(wA, xpad, acc32, msc, out);
}